// Round 2
// baseline (286.142 us; speedup 1.0000x reference)
//
#include <hip/hip_runtime.h>

#define EMB   256
#define NCLS  100
#define NB    64
#define NS    128
#define NL    64
#define CB    20      // classes per block (kernel 2)
#define K2T   320     // threads in kernel 2 (5 waves)

// ---------------------------------------------------------------------------
// Kernel 1: sents[sid][e] = (1/NL) * sum_l emb[tok[sid,l]][e]
// One WAVE per sentence (4 sentences / 256-thread block). Lane covers the
// 256-float row as float4 (64 lanes x 16B = 1KB coalesced per row).
// Tokens are broadcast from lane registers via v_readlane (no LDS, no
// barrier); loads batched 8-deep for memory-level parallelism.
// ---------------------------------------------------------------------------
__global__ __launch_bounds__(256) void k_gather_mean(
    const int* __restrict__ tok, const float* __restrict__ emb,
    float* __restrict__ sents)
{
    const int w    = threadIdx.x >> 6;
    const int lane = threadIdx.x & 63;
    const int sid  = blockIdx.x * 4 + w;          // grid.x = NB*NS/4 = 2048

    const int mytok = tok[(size_t)sid * NL + lane];   // lane l holds token l

    float4 acc = make_float4(0.f, 0.f, 0.f, 0.f);
    for (int i = 0; i < NL; i += 8) {
        float4 v[8];
        #pragma unroll
        for (int j = 0; j < 8; ++j) {
            const int tk = __builtin_amdgcn_readlane(mytok, i + j);  // SGPR
            v[j] = reinterpret_cast<const float4*>(emb + (size_t)tk * EMB)[lane];
        }
        #pragma unroll
        for (int j = 0; j < 8; ++j) {
            acc.x += v[j].x; acc.y += v[j].y; acc.z += v[j].z; acc.w += v[j].w;
        }
    }
    const float s = 1.0f / NL;
    float4 r; r.x = acc.x * s; r.y = acc.y * s; r.z = acc.z * s; r.w = acc.w * s;
    reinterpret_cast<float4*>(sents + (size_t)sid * EMB)[lane] = r;
}

__device__ __forceinline__ float dot4(float4 a, float4 b) {
    return a.x * b.x + a.y * b.y + a.z * b.z + a.w * b.w;
}

// ---------------------------------------------------------------------------
// Kernel 2: logits[b,c] = sum_s softmax_s(ce[c].sents[b,s]) * (mw[c].sents[b,s]) + bias[c]
// Block = (b, 20-class tile), 320 threads. Thread t: sg = t&31 owns sentences
// 4sg..4sg+3; cq = t>>5 owns classes 2cq, 2cq+1. Weights in LDS (float4,
// padded stride, broadcast reads); sents streamed from global (L1/L2 hot).
// ---------------------------------------------------------------------------
__global__ __launch_bounds__(K2T, 2) void k_attn_logits(
    const float* __restrict__ sents, const float* __restrict__ ce,
    const float* __restrict__ mw,    const float* __restrict__ bias,
    float* __restrict__ out)
{
    const int b  = blockIdx.x;
    const int c0 = blockIdx.y * CB;
    const int t  = threadIdx.x;
    const int sg = t & 31;
    const int cq = t >> 5;

    __shared__ float4 wgt[CB][2][66];   // [class][ce|mw][e4], padded 64->66
    __shared__ float  red[CB][2][NS];   // [class][score|tval][s]

    for (int i = t; i < CB * 2 * 64; i += K2T) {
        const int c  = i >> 7;
        const int a  = (i >> 6) & 1;
        const int e4 = i & 63;
        const float* src = a ? mw : ce;
        wgt[c][a][e4] =
            reinterpret_cast<const float4*>(src + (size_t)(c0 + c) * EMB)[e4];
    }
    __syncthreads();

    float scA[4], tvA[4], scB[4], tvB[4];
    #pragma unroll
    for (int j = 0; j < 4; ++j) { scA[j] = tvA[j] = scB[j] = tvB[j] = 0.f; }

    const int cA = 2 * cq, cB = 2 * cq + 1;
    const float* srow = sents + ((size_t)b * NS + sg * 4) * EMB;

    for (int e8 = 0; e8 < EMB / 8; ++e8) {          // 8 floats per step
        float4 sv[4][2];
        #pragma unroll
        for (int j = 0; j < 4; ++j) {
            const float4* rp =
                reinterpret_cast<const float4*>(srow + (size_t)j * EMB) + e8 * 2;
            sv[j][0] = rp[0];
            sv[j][1] = rp[1];
        }
        const float4 wA0 = wgt[cA][0][e8 * 2], wA1 = wgt[cA][0][e8 * 2 + 1];
        const float4 mA0 = wgt[cA][1][e8 * 2], mA1 = wgt[cA][1][e8 * 2 + 1];
        const float4 wB0 = wgt[cB][0][e8 * 2], wB1 = wgt[cB][0][e8 * 2 + 1];
        const float4 mB0 = wgt[cB][1][e8 * 2], mB1 = wgt[cB][1][e8 * 2 + 1];
        #pragma unroll
        for (int j = 0; j < 4; ++j) {
            scA[j] += dot4(sv[j][0], wA0) + dot4(sv[j][1], wA1);
            tvA[j] += dot4(sv[j][0], mA0) + dot4(sv[j][1], mA1);
            scB[j] += dot4(sv[j][0], wB0) + dot4(sv[j][1], wB1);
            tvB[j] += dot4(sv[j][0], mB0) + dot4(sv[j][1], mB1);
        }
    }

    #pragma unroll
    for (int j = 0; j < 4; ++j) {
        red[cA][0][sg * 4 + j] = scA[j];
        red[cA][1][sg * 4 + j] = tvA[j];
        red[cB][0][sg * 4 + j] = scB[j];
        red[cB][1][sg * 4 + j] = tvB[j];
    }
    __syncthreads();

    // Softmax-weighted sum: wave wv handles 4 classes; lane covers s, s+64.
    const int wv   = t >> 6;
    const int lane = t & 63;
    #pragma unroll
    for (int k = 0; k < 4; ++k) {
        const int cl = wv * 4 + k;
        const float x0 = red[cl][0][lane], x1 = red[cl][0][lane + 64];
        float m = fmaxf(x0, x1);
        #pragma unroll
        for (int d = 1; d < 64; d <<= 1) m = fmaxf(m, __shfl_xor(m, d));
        const float p0 = __expf(x0 - m), p1 = __expf(x1 - m);
        const float t0 = red[cl][1][lane], t1 = red[cl][1][lane + 64];
        float sp = p0 + p1;
        float st = p0 * t0 + p1 * t1;
        #pragma unroll
        for (int d = 1; d < 64; d <<= 1) {
            sp += __shfl_xor(sp, d);
            st += __shfl_xor(st, d);
        }
        if (lane == 0)
            out[(size_t)b * NCLS + c0 + cl] = st / sp + bias[c0 + cl];
    }
}

extern "C" void kernel_launch(void* const* d_in, const int* in_sizes, int n_in,
                              void* d_out, int out_size, void* d_ws, size_t ws_size,
                              hipStream_t stream)
{
    const int*   tok  = (const int*)  d_in[0];   // (B,S,L) int32
    const float* emb  = (const float*)d_in[1];   // (VOCAB, EMB)
    const float* ce   = (const float*)d_in[2];   // (NCLS, EMB)
    const float* mw   = (const float*)d_in[3];   // (NCLS, EMB)
    const float* bias = (const float*)d_in[4];   // (NCLS, 1)
    float* out   = (float*)d_out;                // (B, NCLS)
    float* sents = (float*)d_ws;                 // NB*NS*EMB floats = 8 MB

    k_gather_mean<<<NB * NS / 4, 256, 0, stream>>>(tok, emb, sents);
    k_attn_logits<<<dim3(NB, NCLS / CB), K2T, 0, stream>>>(sents, ce, mw, bias, out);
}